// Round 1
// baseline (349.873 us; speedup 1.0000x reference)
//
#include <hip/hip_runtime.h>

#define RAD 5
#define BX 64              // output tile width (pixels)
#define BY 32              // output tile height
#define PX 2               // pixels per thread in x
#define PY 2               // pixels per thread in y
#define NTX 32             // threads in x (NTX*PX == BX)
#define NTY 16             // threads in y (NTY*PY == BY)
#define NT 512
#define TW (BX + 2*RAD)    // 74 halo tile width
#define TH (BY + 2*RAD)    // 42 halo tile height
#define HALF (TW/2)        // 37: parity-split offset (even cols 0..36, odd 37..73)

#define LOG2E 1.44269504f
#define CLAMP2 14426.950f  // 1e4 * log2(e)
// 128*log2(x) ~= f*(C1 + f*(C2 + f*C3)), f = x-1  (cubic ln series * 128/ln2)
#define PC1 184.664963f
#define PC2 -92.3324814f
#define PC3 61.5549876f

// kSA[ady][adx] = kLG[ady]+kLG[adx], kLG[d] = log2(exp(-d*d/8)) = -d*d/(8*ln2).
// Row ady==6 is the PY edge-row sentinel: -1e30 -> exp2 -> weight 0.
__device__ __constant__ const float kSA[7][6] = {
    {0.0f, -0.18033688f, -0.72134752f, -1.62303192f, -2.88539008f, -4.50842200f},
    {-0.18033688f, -0.36067376f, -0.90168440f, -1.80336880f, -3.06572696f, -4.68875888f},
    {-0.72134752f, -0.90168440f, -1.44269504f, -2.34437944f, -3.60673760f, -5.22976952f},
    {-1.62303192f, -1.80336880f, -2.34437944f, -3.24606384f, -4.50842200f, -6.13145392f},
    {-2.88539008f, -3.06572696f, -3.60673760f, -4.50842200f, -5.77078016f, -7.39381208f},
    {-4.50842200f, -4.68875888f, -5.22976952f, -6.13145392f, -7.39381208f, -9.01684400f},
    {-1e30f, -1e30f, -1e30f, -1e30f, -1e30f, -1e30f}};
// kINVD[ady][adx] = 1/sqrt(dy^2+dx^2); center sentinel 1e30 -> min() clamps to CLAMP2.
// Row 6 only reached with kSA=-1e30 (weight forced 0); values finite to avoid NaN.
__device__ __constant__ const float kINVD[7][6] = {
    {1e30f,       1.0f,        0.5f,        0.33333333f, 0.25f,       0.2f},
    {1.0f,        0.70710678f, 0.44721360f, 0.31622777f, 0.24253563f, 0.19611614f},
    {0.5f,        0.44721360f, 0.35355339f, 0.27735010f, 0.22360680f, 0.18569534f},
    {0.33333333f, 0.31622777f, 0.27735010f, 0.23570226f, 0.2f,        0.17149859f},
    {0.25f,       0.24253563f, 0.22360680f, 0.2f,        0.17677670f, 0.15617376f},
    {0.2f,        0.19611614f, 0.18569534f, 0.17149859f, 0.15617376f, 0.14142136f},
    {0.16666667f, 0.16439899f, 0.15811388f, 0.14907120f, 0.13867505f, 0.12803688f}};

__global__ __launch_bounds__(512, 4) void bilateral_kernel(
    const float* __restrict__ col, const float* __restrict__ nrm,
    const float* __restrict__ zdz, float* __restrict__ out,
    int H, int W) {
  // Parity-split layout: column c stored at phys (c>>1) + (c&1)*HALF.
  // A wave's tap reads hit same-parity columns (c = 2*tx + u) -> 32 consecutive
  // elements per half-wave -> conflict-free ds_read_b128/b64.
  __shared__ float4 s_w[TH][TW];  // nrm.xyz, z   (weight inputs, exact fp32)
  __shared__ uint2  s_c[TH][TW];  // col.rgb as rounded bf16: {g|r packed, b<<16}

  const int bx = blockIdx.x, by = blockIdx.y, bz = blockIdx.z;
  const int gx0 = bx * BX - RAD;
  const int gy0 = by * BY - RAD;
  const int tid = threadIdx.x;
  const int plane = bz * H * W;

  // ---- stage halo tile into LDS (OOB -> zeros => weight 0, matches mask) ----
  for (int i = tid; i < TH * TW; i += NT) {
    const int r = i / TW;
    const int c = i - r * TW;
    const int pc = (c >> 1) + (c & 1) * HALF;
    const int gy = gy0 + r, gx = gx0 + c;
    float4 wv = make_float4(0.f, 0.f, 0.f, 0.f);
    uint2 cv = make_uint2(0u, 0u);
    if ((unsigned)gy < (unsigned)H && (unsigned)gx < (unsigned)W) {
      const int pix = plane + gy * W + gx;
      const float* np_ = nrm + pix * 3;
      wv.x = np_[0]; wv.y = np_[1]; wv.z = np_[2];
      wv.w = zdz[pix * 2];  // depth
      const float* cp = col + pix * 3;
      // round-to-nearest bf16, kept in fp32 bit positions
      const unsigned ur = (__float_as_uint(cp[0]) + 0x8000u) >> 16;
      const unsigned ug = (__float_as_uint(cp[1]) + 0x8000u) & 0xffff0000u;
      const unsigned ub = (__float_as_uint(cp[2]) + 0x8000u) & 0xffff0000u;
      cv.x = ur | ug;   // r in low half (shl16 to decode), g in high half
      cv.y = ub;        // b already in fp32-high position
    }
    s_w[r][pc] = wv;
    s_c[r][pc] = cv;
  }
  __syncthreads();

  const int tx = tid & (NTX - 1);
  const int ty = tid >> 5;
  const int oy0 = by * BY + ty * PY;
  const int ox0 = bx * BX + tx * PX;

  float cnx[2][2], cny[2][2], cnz[2][2], czv[2][2], rc2[2][2];
  float accx[2][2], accy[2][2], accz[2][2], accw[2][2];
#pragma unroll
  for (int q = 0; q < 2; ++q) {
#pragma unroll
    for (int p = 0; p < 2; ++p) {
      const int c = tx * PX + RAD + p;
      const int pc = (c >> 1) + (c & 1) * HALF;
      const float4 wv = s_w[ty * PY + RAD + q][pc];
      cnx[q][p] = wv.x; cny[q][p] = wv.y; cnz[q][p] = wv.z;
      czv[q][p] = wv.w;
      const float cdz = zdz[(plane + (oy0 + q) * W + ox0 + p) * 2 + 1];  // center |dz|
      rc2[q][p] = LOG2E / cdz;  // inf ok: min() clamp below
      accx[q][p] = 0.f; accy[q][p] = 0.f; accz[q][p] = 0.f; accw[q][p] = 0.f;
    }
  }

  // ---- 12 tap rows serve PY=2 center rows: dy(q) = trow - RAD - q ----
#pragma unroll 1
  for (int trow = 0; trow < 2 * RAD + PY; ++trow) {
    const int dy0 = trow - RAD;
    const int ady0 = dy0 < 0 ? -dy0 : dy0;          // 0..6 (6 => weight 0 row)
    const int dy1 = trow - RAD - 1;
    const int ady1 = dy1 < 0 ? -dy1 : dy1;          // 0..6
    const float* __restrict__ sa0 = kSA[ady0];      // wave-uniform -> s_load
    const float* __restrict__ sa1 = kSA[ady1];
    const float* __restrict__ iv0 = kINVD[ady0];
    const float* __restrict__ iv1 = kINVD[ady1];
    float il20[6][2], il21[6][2];
#pragma unroll
    for (int j = 0; j < 6; ++j) {
      const float v0 = iv0[j], v1 = iv1[j];
#pragma unroll
      for (int p = 0; p < 2; ++p) {
        il20[j][p] = fminf(rc2[0][p] * v0, CLAMP2);
        il21[j][p] = fminf(rc2[1][p] * v1, CLAMP2);
      }
    }
    const float4* __restrict__ rowW = &s_w[ty * PY + trow][tx];
    const uint2* __restrict__ rowC = &s_c[ty * PY + trow][tx];

#pragma unroll
    for (int u = 0; u < 2 * RAD + PX; ++u) {  // 12 tap columns serve PX pixels
      const int off = (u >> 1) + (u & 1) * HALF;  // parity-split, compile-time
      const float4 wv = rowW[off];
      const uint2 cv = rowC[off];
      const float tcr = __uint_as_float(cv.x << 16);
      const float tcg = __uint_as_float(cv.x & 0xffff0000u);
      const float tcb = __uint_as_float(cv.y);
#pragma unroll
      for (int p = 0; p < 2; ++p) {
        const int dx = u - RAD - p;
        if (dx < -RAD || dx > RAD) continue;
        const int adx = dx < 0 ? -dx : dx;
        {  // center row q = 0
          const float d1 = fmaf(wv.x, cnx[0][p],
                           fmaf(wv.y, cny[0][p], fmaf(wv.z, cnz[0][p], -1.0f)));
          const float f = fmaxf(d1, -1.0f);
          const float dzv = wv.w - czv[0][p];
          const float ct = fmaf(-fabsf(dzv), il20[adx][p], sa0[adx]);
          const float t1 = fmaf(f, PC3, PC2);
          const float t2 = fmaf(f, t1, PC1);
          const float e = fmaf(f, t2, ct);
          const float w = __builtin_amdgcn_exp2f(e);
          accx[0][p] = fmaf(tcr, w, accx[0][p]);
          accy[0][p] = fmaf(tcg, w, accy[0][p]);
          accz[0][p] = fmaf(tcb, w, accz[0][p]);
          accw[0][p] += w;
        }
        {  // center row q = 1
          const float d1 = fmaf(wv.x, cnx[1][p],
                           fmaf(wv.y, cny[1][p], fmaf(wv.z, cnz[1][p], -1.0f)));
          const float f = fmaxf(d1, -1.0f);
          const float dzv = wv.w - czv[1][p];
          const float ct = fmaf(-fabsf(dzv), il21[adx][p], sa1[adx]);
          const float t1 = fmaf(f, PC3, PC2);
          const float t2 = fmaf(f, t1, PC1);
          const float e = fmaf(f, t2, ct);
          const float w = __builtin_amdgcn_exp2f(e);
          accx[1][p] = fmaf(tcr, w, accx[1][p]);
          accy[1][p] = fmaf(tcg, w, accy[1][p]);
          accz[1][p] = fmaf(tcb, w, accz[1][p]);
          accw[1][p] += w;
        }
      }
    }
  }

#pragma unroll
  for (int q = 0; q < 2; ++q) {
#pragma unroll
    for (int p = 0; p < 2; ++p) {
      const int pix = plane + (oy0 + q) * W + ox0 + p;
      const float inv = 1.0f / accw[q][p];  // center tap weight==1 => accw>=1
      float* op = out + pix * 3;
      op[0] = accx[q][p] * inv;
      op[1] = accy[q][p] * inv;
      op[2] = accz[q][p] * inv;
    }
  }
}

extern "C" void kernel_launch(void* const* d_in, const int* in_sizes, int n_in,
                              void* d_out, int out_size, void* d_ws, size_t ws_size,
                              hipStream_t stream) {
  const float* col = (const float*)d_in[0];
  const float* nrm = (const float*)d_in[1];
  const float* zdz = (const float*)d_in[2];
  float* out = (float*)d_out;
  const int H = 1024, W = 1024;
  const int B = in_sizes[0] / (3 * H * W);
  dim3 grid(W / BX, H / BY, B);
  bilateral_kernel<<<grid, dim3(NT), 0, stream>>>(col, nrm, zdz, out, H, W);
}

// Round 2
// 337.742 us; speedup vs baseline: 1.0359x; 1.0359x over previous
//
#include <hip/hip_runtime.h>

#define RAD 5
#define BX 32              // output tile width (pixels)
#define BY 16              // output tile height
#define PX 2               // pixels per thread in x
#define NTX 16             // threads in x (NTX*PX == BX)
#define TW (BX + 2*RAD)    // 42 halo tile width
#define TH (BY + 2*RAD)    // 26 halo tile height
#define HALF (TW/2)        // 21: parity-split offset (even cols 0..20, odd 21..41)

#define LOG2E 1.44269504f
#define CLAMP2 14426.950f  // 1e4 * log2(e)
// 128*log2(x) ~= f*(C1 + f*(C2 + f*C3)), f = x-1  (cubic ln series * 128/ln2)
#define PC1 184.664963f
#define PC2 -92.3324814f
#define PC3 61.5549876f

// kLG[|d|] = log2(exp(-d*d/8)) = -d*d/(8*ln2)
__device__ __constant__ const float kLG[6] = {
    0.0f, -0.18033688f, -0.72134752f, -1.62303192f, -2.88539008f, -4.50842200f};
// kINVD[|dy|][|dx|] = 1/sqrt(dy^2+dx^2); center sentinel 1e30 -> min() clamps
__device__ __constant__ const float kINVD[6][6] = {
    {1e30f,       1.0f,        0.5f,        0.33333333f, 0.25f,       0.2f},
    {1.0f,        0.70710678f, 0.44721360f, 0.31622777f, 0.24253563f, 0.19611614f},
    {0.5f,        0.44721360f, 0.35355339f, 0.27735010f, 0.22360680f, 0.18569534f},
    {0.33333333f, 0.31622777f, 0.27735010f, 0.23570226f, 0.2f,        0.17149859f},
    {0.25f,       0.24253563f, 0.22360680f, 0.2f,        0.17677670f, 0.15617376f},
    {0.2f,        0.19611614f, 0.18569534f, 0.17149859f, 0.15617376f, 0.14142136f}};

// launch_bounds(256, 6): 6 blocks/CU (LDS permits 163840/26368 = 6.2).
// Round-0's (256,4) was the binding occupancy cap (50% -> 75%).
__global__ __launch_bounds__(256, 6) void bilateral_kernel(
    const float* __restrict__ col, const float* __restrict__ nrm,
    const float* __restrict__ zdz, float* __restrict__ out,
    int H, int W) {
  // Parity-split layout: logical column c stored at phys (c>>1) + (c&1)*HALF.
  // Tap reads hit logical col 2*tx+u -> phys tx + const -> 16 consecutive
  // elements per quarter-wave -> conflict-free ds_read_b128/b64 (round-1
  // measured: bank conflicts 1.76e7 -> 1.19e6 with this layout).
  __shared__ float4 s_w[TH][TW];  // nrm.xyz, z   (weight inputs, exact fp32)
  __shared__ uint2  s_c[TH][TW];  // col.rgb as rounded bf16: {g|r packed, b<<16}

  const int bx = blockIdx.x, by = blockIdx.y, bz = blockIdx.z;
  const int gx0 = bx * BX - RAD;
  const int gy0 = by * BY - RAD;
  const int tid = threadIdx.x;
  const int plane = bz * H * W;

  // ---- stage halo tile into LDS (OOB -> zeros => weight 0, matches mask) ----
  for (int i = tid; i < TH * TW; i += 256) {
    const int r = i / TW;
    const int c = i - r * TW;
    const int pc = (c >> 1) + (c & 1) * HALF;
    const int gy = gy0 + r, gx = gx0 + c;
    float4 wv = make_float4(0.f, 0.f, 0.f, 0.f);
    uint2 cv = make_uint2(0u, 0u);
    if ((unsigned)gy < (unsigned)H && (unsigned)gx < (unsigned)W) {
      const int pix = plane + gy * W + gx;
      const float* np_ = nrm + pix * 3;
      wv.x = np_[0]; wv.y = np_[1]; wv.z = np_[2];
      wv.w = zdz[pix * 2];  // depth
      const float* cp = col + pix * 3;
      // round-to-nearest bf16, kept in fp32 bit positions
      const unsigned ur = (__float_as_uint(cp[0]) + 0x8000u) >> 16;
      const unsigned ug = (__float_as_uint(cp[1]) + 0x8000u) & 0xffff0000u;
      const unsigned ub = (__float_as_uint(cp[2]) + 0x8000u) & 0xffff0000u;
      cv.x = ur | ug;   // r in low half (shl16 to decode), g in high half
      cv.y = ub;        // b already in fp32-high position
    }
    s_w[r][pc] = wv;
    s_c[r][pc] = cv;
  }
  __syncthreads();

  const int tx = tid & (NTX - 1);
  const int ty = tid >> 4;
  const int ly = ty + RAD;
  const int oy = by * BY + ty;
  const int ox0 = bx * BX + tx * PX;

  float cnx[PX], cny[PX], cnz[PX], czv[PX], rc2[PX];
  float accx[PX], accy[PX], accz[PX], accw[PX];
#pragma unroll
  for (int p = 0; p < PX; ++p) {
    const int c = tx * PX + RAD + p;
    const int pc = (c >> 1) + (c & 1) * HALF;
    const float4 wv = s_w[ly][pc];
    cnx[p] = wv.x; cny[p] = wv.y; cnz[p] = wv.z;
    czv[p] = wv.w;
    const float cdz = zdz[(plane + oy * W + ox0 + p) * 2 + 1];  // center |dz|
    rc2[p] = LOG2E / cdz;  // inf ok: min() clamp below
    accx[p] = 0.f; accy[p] = 0.f; accz[p] = 0.f; accw[p] = 0.f;
  }

#pragma unroll 1
  for (int dy = -RAD; dy <= RAD; ++dy) {
    const int ady = dy < 0 ? -dy : dy;
    const float kg_ady = kLG[ady];      // wave-uniform (SGPR)
    const float* irow = kINVD[ady];     // wave-uniform row pointer
    float sA[6];                         // kLG[adx]+kLG[ady]  (SGPR)
    float il2s[6][PX];
#pragma unroll
    for (int j = 0; j < 6; ++j) {
      sA[j] = kLG[j] + kg_ady;
      const float iv = irow[j];
#pragma unroll
      for (int p = 0; p < PX; ++p) il2s[j][p] = fminf(rc2[p] * iv, CLAMP2);
    }

    // logical col = 2*tx + u -> phys = tx + (u>>1) + (u&1)*HALF
    const float4* rowW = &s_w[ly + dy][tx];
    const uint2* rowC = &s_c[ly + dy][tx];

#pragma unroll
    for (int u = 0; u < 2 * RAD + PX; ++u) {  // 12 tap columns serve PX pixels
      const int off = (u >> 1) + (u & 1) * HALF;  // compile-time per u
      const float4 wv = rowW[off];
      const uint2 cv = rowC[off];
      const float tr = __uint_as_float(cv.x << 16);
      const float tg = __uint_as_float(cv.x & 0xffff0000u);
      const float tb = __uint_as_float(cv.y);
#pragma unroll
      for (int p = 0; p < PX; ++p) {
        const int dx = u - RAD - p;
        if (dx < -RAD || dx > RAD) continue;
        const int adx = dx < 0 ? -dx : dx;
        // f = clamp(dot,?) - 1, with the -1 folded into the dot chain
        const float d1 = fmaf(wv.x, cnx[p],
                         fmaf(wv.y, cny[p], fmaf(wv.z, cnz[p], -1.0f)));
        const float f = fmaxf(d1, -1.0f);
        // ct = sA - |z_t - z_c| * il2   (exponent sans normal term)
        const float dz = wv.w - czv[p];
        const float ct = fmaf(-fabsf(dz), il2s[adx][p], sA[adx]);
        // e = 128*log2(dot) + ct via cubic in f; f=-1 -> e<=-338 -> w==0
        const float t1 = fmaf(f, PC3, PC2);
        const float t2 = fmaf(f, t1, PC1);
        const float e = fmaf(f, t2, ct);
        const float w = __builtin_amdgcn_exp2f(e);
        accx[p] = fmaf(tr, w, accx[p]);
        accy[p] = fmaf(tg, w, accy[p]);
        accz[p] = fmaf(tb, w, accz[p]);
        accw[p] += w;
      }
    }
  }

#pragma unroll
  for (int p = 0; p < PX; ++p) {
    const int pix = plane + oy * W + ox0 + p;
    const float inv = 1.0f / accw[p];  // center tap weight==1 => accw>=1
    float* op = out + pix * 3;
    op[0] = accx[p] * inv;
    op[1] = accy[p] * inv;
    op[2] = accz[p] * inv;
  }
}

extern "C" void kernel_launch(void* const* d_in, const int* in_sizes, int n_in,
                              void* d_out, int out_size, void* d_ws, size_t ws_size,
                              hipStream_t stream) {
  const float* col = (const float*)d_in[0];
  const float* nrm = (const float*)d_in[1];
  const float* zdz = (const float*)d_in[2];
  float* out = (float*)d_out;
  const int H = 1024, W = 1024;
  const int B = in_sizes[0] / (3 * H * W);
  dim3 grid(W / BX, H / BY, B);
  bilateral_kernel<<<grid, dim3(256), 0, stream>>>(col, nrm, zdz, out, H, W);
}

// Round 4
// 331.883 us; speedup vs baseline: 1.0542x; 1.0177x over previous
//
#include <hip/hip_runtime.h>

#define RAD 5
#define BX 64              // output tile width (pixels)
#define BY 16              // output tile height
#define PX 2               // pixels per thread in x
#define NTX 32             // threads in x (NTX*PX == BX) -> tx spans half-wave
#define NTY 16             // threads in y
#define NT 512
#define TW (BX + 2*RAD)    // 74 halo tile width
#define TH (BY + 2*RAD)    // 26 halo tile height
#define HALF (TW/2)        // 37: parity-split offset (even cols 0..36, odd 37..73)

#define LOG2E 1.44269504f
#define CLAMP2 14426.950f  // 1e4 * log2(e)
// 128*log2(x) ~= f*(C1 + f*(C2 + f*C3)), f = x-1  (cubic ln series * 128/ln2)
#define PC1 184.664963f
#define PC2 -92.3324814f
#define PC3 61.5549876f

// kLG[|d|] = log2(exp(-d*d/8)) = -d*d/(8*ln2)
__device__ __constant__ const float kLG[6] = {
    0.0f, -0.18033688f, -0.72134752f, -1.62303192f, -2.88539008f, -4.50842200f};
// kINVD[|dy|][|dx|] = 1/sqrt(dy^2+dx^2); center sentinel 1e30 -> min() clamps
__device__ __constant__ const float kINVD[6][6] = {
    {1e30f,       1.0f,        0.5f,        0.33333333f, 0.25f,       0.2f},
    {1.0f,        0.70710678f, 0.44721360f, 0.31622777f, 0.24253563f, 0.19611614f},
    {0.5f,        0.44721360f, 0.35355339f, 0.27735010f, 0.22360680f, 0.18569534f},
    {0.33333333f, 0.31622777f, 0.27735010f, 0.23570226f, 0.2f,        0.17149859f},
    {0.25f,       0.24253563f, 0.22360680f, 0.2f,        0.17677670f, 0.15617376f},
    {0.2f,        0.19611614f, 0.18569534f, 0.17149859f, 0.15617376f, 0.14142136f}};

// 512 threads = 8 waves; 3 blocks/CU (LDS 46.2 KB -> 163840/46336 = 3.5) ->
// 24 waves/CU = 6 waves/EU = 75% occupancy.  NTX=32: each half-wave reads 32
// consecutive LDS elements per tap (r1-measured conflict-free: 1.19e6 total
// vs 1.76e7 for the 16-lane-group geometry).
__global__ __launch_bounds__(512, 6) void bilateral_kernel(
    const float* __restrict__ col, const float* __restrict__ nrm,
    const float* __restrict__ zdz, float* __restrict__ out,
    int H, int W) {
  // Parity-split layout: logical column c stored at phys (c>>1) + (c&1)*HALF.
  // Tap read logical col = 2*tx + u -> phys = tx + (u>>1) + (u&1)*HALF:
  // per half-wave a run of 32 consecutive elements -> linear, conflict-free.
  __shared__ float4 s_w[TH][TW];  // nrm.xyz, z   (weight inputs, exact fp32)
  __shared__ uint2  s_c[TH][TW];  // col.rgb as rounded bf16: {g|r packed, b<<16}

  const int bx = blockIdx.x, by = blockIdx.y, bz = blockIdx.z;
  const int gx0 = bx * BX - RAD;
  const int gy0 = by * BY - RAD;
  const int tid = threadIdx.x;
  const int plane = bz * H * W;

  // ---- stage halo tile into LDS (OOB -> zeros => weight 0, matches mask) ----
  for (int i = tid; i < TH * TW; i += NT) {
    const int r = i / TW;
    const int c = i - r * TW;
    const int pc = (c >> 1) + (c & 1) * HALF;
    const int gy = gy0 + r, gx = gx0 + c;
    float4 wv = make_float4(0.f, 0.f, 0.f, 0.f);
    uint2 cv = make_uint2(0u, 0u);
    if ((unsigned)gy < (unsigned)H && (unsigned)gx < (unsigned)W) {
      const int pix = plane + gy * W + gx;
      const float* np_ = nrm + pix * 3;
      wv.x = np_[0]; wv.y = np_[1]; wv.z = np_[2];
      wv.w = zdz[pix * 2];  // depth
      const float* cp = col + pix * 3;
      // round-to-nearest bf16, kept in fp32 bit positions
      const unsigned ur = (__float_as_uint(cp[0]) + 0x8000u) >> 16;
      const unsigned ug = (__float_as_uint(cp[1]) + 0x8000u) & 0xffff0000u;
      const unsigned ub = (__float_as_uint(cp[2]) + 0x8000u) & 0xffff0000u;
      cv.x = ur | ug;   // r in low half (shl16 to decode), g in high half
      cv.y = ub;        // b already in fp32-high position
    }
    s_w[r][pc] = wv;
    s_c[r][pc] = cv;
  }
  __syncthreads();

  const int tx = tid & (NTX - 1);
  const int ty = tid >> 5;
  const int ly = ty + RAD;
  const int oy = by * BY + ty;
  const int ox0 = bx * BX + tx * PX;

  float cnx[PX], cny[PX], cnz[PX], czv[PX], rc2[PX];
  float accx[PX], accy[PX], accz[PX], accw[PX];
#pragma unroll
  for (int p = 0; p < PX; ++p) {
    const int c = tx * PX + RAD + p;
    const int pc = (c >> 1) + (c & 1) * HALF;
    const float4 wv = s_w[ly][pc];
    cnx[p] = wv.x; cny[p] = wv.y; cnz[p] = wv.z;
    czv[p] = wv.w;
    const float cdz = zdz[(plane + oy * W + ox0 + p) * 2 + 1];  // center |dz|
    rc2[p] = LOG2E / cdz;  // inf ok: min() clamp below
    accx[p] = 0.f; accy[p] = 0.f; accz[p] = 0.f; accw[p] = 0.f;
  }

#pragma unroll 1
  for (int dy = -RAD; dy <= RAD; ++dy) {
    const int ady = dy < 0 ? -dy : dy;
    const float kg_ady = kLG[ady];      // wave-uniform (SGPR)
    const float* irow = kINVD[ady];     // wave-uniform row pointer
    float sA[6];                         // kLG[adx]+kLG[ady]  (SGPR)
    float il2s[6][PX];
#pragma unroll
    for (int j = 0; j < 6; ++j) {
      sA[j] = kLG[j] + kg_ady;
      const float iv = irow[j];
#pragma unroll
      for (int p = 0; p < PX; ++p) il2s[j][p] = fminf(rc2[p] * iv, CLAMP2);
    }

    // logical col = 2*tx + u -> phys = tx + (u>>1) + (u&1)*HALF
    const float4* rowW = &s_w[ly + dy][tx];
    const uint2* rowC = &s_c[ly + dy][tx];

#pragma unroll
    for (int u = 0; u < 2 * RAD + PX; ++u) {  // 12 tap columns serve PX pixels
      const int off = (u >> 1) + (u & 1) * HALF;  // compile-time per u
      const float4 wv = rowW[off];
      const uint2 cv = rowC[off];
      const float tr = __uint_as_float(cv.x << 16);
      const float tg = __uint_as_float(cv.x & 0xffff0000u);
      const float tb = __uint_as_float(cv.y);
#pragma unroll
      for (int p = 0; p < PX; ++p) {
        const int dx = u - RAD - p;
        if (dx < -RAD || dx > RAD) continue;
        const int adx = dx < 0 ? -dx : dx;
        // f = clamp(dot,?) - 1, with the -1 folded into the dot chain
        const float d1 = fmaf(wv.x, cnx[p],
                         fmaf(wv.y, cny[p], fmaf(wv.z, cnz[p], -1.0f)));
        const float f = fmaxf(d1, -1.0f);
        // ct = sA - |z_t - z_c| * il2   (exponent sans normal term)
        const float dz = wv.w - czv[p];
        const float ct = fmaf(-fabsf(dz), il2s[adx][p], sA[adx]);
        // e = 128*log2(dot) + ct via cubic in f; f=-1 -> e<=-338 -> w==0
        const float t1 = fmaf(f, PC3, PC2);
        const float t2 = fmaf(f, t1, PC1);
        const float e = fmaf(f, t2, ct);
        const float w = __builtin_amdgcn_exp2f(e);
        accx[p] = fmaf(tr, w, accx[p]);
        accy[p] = fmaf(tg, w, accy[p]);
        accz[p] = fmaf(tb, w, accz[p]);
        accw[p] += w;
      }
    }
  }

#pragma unroll
  for (int p = 0; p < PX; ++p) {
    const int pix = plane + oy * W + ox0 + p;
    const float inv = 1.0f / accw[p];  // center tap weight==1 => accw>=1
    float* op = out + pix * 3;
    op[0] = accx[p] * inv;
    op[1] = accy[p] * inv;
    op[2] = accz[p] * inv;
  }
}

extern "C" void kernel_launch(void* const* d_in, const int* in_sizes, int n_in,
                              void* d_out, int out_size, void* d_ws, size_t ws_size,
                              hipStream_t stream) {
  const float* col = (const float*)d_in[0];
  const float* nrm = (const float*)d_in[1];
  const float* zdz = (const float*)d_in[2];
  float* out = (float*)d_out;
  const int H = 1024, W = 1024;
  const int B = in_sizes[0] / (3 * H * W);
  dim3 grid(W / BX, H / BY, B);
  bilateral_kernel<<<grid, dim3(NT), 0, stream>>>(col, nrm, zdz, out, H, W);
}

// Round 5
// 311.077 us; speedup vs baseline: 1.1247x; 1.0669x over previous
//
#include <hip/hip_runtime.h>

#define RAD 5
#define BX 64              // output tile width (pixels)
#define BY 16              // output tile height
#define PX 2               // pixels per thread in x
#define NTX 32             // threads in x (NTX*PX == BX) -> tx spans half-wave
#define NTY 16             // threads in y
#define NT 512
#define TW (BX + 2*RAD)    // 74 halo tile width
#define TH (BY + 2*RAD)    // 26 halo tile height
#define HALF (TW/2)        // 37: parity-split offset (even cols 0..36, odd 37..73)
#define NU (2*RAD + PX)    // 12 tap columns per row

#define LOG2E 1.44269504f
#define CLAMP2 14426.950f  // 1e4 * log2(e)
// 128*log2(x) ~= f*(C1 + f*(C2 + f*C3)), f = x-1  (cubic ln series * 128/ln2)
#define PC1 184.664963f
#define PC2 -92.3324814f
#define PC3 61.5549876f

// kLG[|d|] = log2(exp(-d*d/8)) = -d*d/(8*ln2)
__device__ __constant__ const float kLG[6] = {
    0.0f, -0.18033688f, -0.72134752f, -1.62303192f, -2.88539008f, -4.50842200f};
// kINVD[|dy|][|dx|] = 1/sqrt(dy^2+dx^2); center sentinel 1e30 -> min() clamps
__device__ __constant__ const float kINVD[6][6] = {
    {1e30f,       1.0f,        0.5f,        0.33333333f, 0.25f,       0.2f},
    {1.0f,        0.70710678f, 0.44721360f, 0.31622777f, 0.24253563f, 0.19611614f},
    {0.5f,        0.44721360f, 0.35355339f, 0.27735010f, 0.22360680f, 0.18569534f},
    {0.33333333f, 0.31622777f, 0.27735010f, 0.23570226f, 0.2f,        0.17149859f},
    {0.25f,       0.24253563f, 0.22360680f, 0.2f,        0.17677670f, 0.15617376f},
    {0.2f,        0.19611614f, 0.18569534f, 0.17149859f, 0.15617376f, 0.14142136f}};

// (512,4): VGPR budget 128 (was 40 used at (512,6) -> no prefetch depth).
// 4 waves/SIMD = 50% occupancy — the best-measured regime (r0).
// NTX=32 parity-split geometry: conflict-free LDS reads (r4: 1.47e6 vs 1.76e7).
__global__ __launch_bounds__(512, 4) void bilateral_kernel(
    const float* __restrict__ col, const float* __restrict__ nrm,
    const float* __restrict__ zdz, float* __restrict__ out,
    int H, int W) {
  // Parity-split layout: logical column c stored at phys (c>>1) + (c&1)*HALF.
  // Tap read logical col = 2*tx + u -> phys = tx + (u>>1) + (u&1)*HALF:
  // per half-wave a run of 32 consecutive elements -> linear, conflict-free.
  __shared__ float4 s_w[TH][TW];  // nrm.xyz, z   (weight inputs, exact fp32)
  __shared__ uint2  s_c[TH][TW];  // col.rgb as rounded bf16: {g|r packed, b<<16}

  const int bx = blockIdx.x, by = blockIdx.y, bz = blockIdx.z;
  const int gx0 = bx * BX - RAD;
  const int gy0 = by * BY - RAD;
  const int tid = threadIdx.x;
  const int plane = bz * H * W;

  // ---- stage halo tile into LDS (OOB -> zeros => weight 0, matches mask) ----
  for (int i = tid; i < TH * TW; i += NT) {
    const int r = i / TW;
    const int c = i - r * TW;
    const int pc = (c >> 1) + (c & 1) * HALF;
    const int gy = gy0 + r, gx = gx0 + c;
    float4 wv = make_float4(0.f, 0.f, 0.f, 0.f);
    uint2 cv = make_uint2(0u, 0u);
    if ((unsigned)gy < (unsigned)H && (unsigned)gx < (unsigned)W) {
      const int pix = plane + gy * W + gx;
      const float* np_ = nrm + pix * 3;
      wv.x = np_[0]; wv.y = np_[1]; wv.z = np_[2];
      wv.w = zdz[pix * 2];  // depth
      const float* cp = col + pix * 3;
      // round-to-nearest bf16, kept in fp32 bit positions
      const unsigned ur = (__float_as_uint(cp[0]) + 0x8000u) >> 16;
      const unsigned ug = (__float_as_uint(cp[1]) + 0x8000u) & 0xffff0000u;
      const unsigned ub = (__float_as_uint(cp[2]) + 0x8000u) & 0xffff0000u;
      cv.x = ur | ug;   // r in low half (shl16 to decode), g in high half
      cv.y = ub;        // b already in fp32-high position
    }
    s_w[r][pc] = wv;
    s_c[r][pc] = cv;
  }
  __syncthreads();

  const int tx = tid & (NTX - 1);
  const int ty = tid >> 5;
  const int ly = ty + RAD;
  const int oy = by * BY + ty;
  const int ox0 = bx * BX + tx * PX;

  float cnx[PX], cny[PX], cnz[PX], czv[PX], rc2[PX];
  float accx[PX], accy[PX], accz[PX], accw[PX];
#pragma unroll
  for (int p = 0; p < PX; ++p) {
    const int c = tx * PX + RAD + p;
    const int pc = (c >> 1) + (c & 1) * HALF;
    const float4 wv = s_w[ly][pc];
    cnx[p] = wv.x; cny[p] = wv.y; cnz[p] = wv.z;
    czv[p] = wv.w;
    const float cdz = zdz[(plane + oy * W + ox0 + p) * 2 + 1];  // center |dz|
    rc2[p] = LOG2E / cdz;  // inf ok: min() clamp below
    accx[p] = 0.f; accy[p] = 0.f; accz[p] = 0.f; accw[p] = 0.f;
  }

#pragma unroll 1
  for (int dy = -RAD; dy <= RAD; ++dy) {
    const int ady = dy < 0 ? -dy : dy;

    // ---- batch-prefetch the whole tap row into registers FIRST ----
    // 12 x (b128 + b64) issued back-to-back; static indices -> stays in VGPRs
    // (rule #20). The il2s table math below then overlaps the LDS latency,
    // and the compute loop gets counted-lgkmcnt waits instead of one
    // read->wait->use stall per u (r0-r4 invariant: VGPR<=48 => no prefetch
    // depth => LDS latency serialized with VALU; pipes summed, not overlapped).
    const float4* rowW = &s_w[ly + dy][tx];
    const uint2* rowC = &s_c[ly + dy][tx];
    float4 wvs[NU];
    uint2 cvs[NU];
#pragma unroll
    for (int u = 0; u < NU; ++u) {
      const int off = (u >> 1) + (u & 1) * HALF;  // compile-time per u
      wvs[u] = rowW[off];
      cvs[u] = rowC[off];
    }

    const float kg_ady = kLG[ady];      // wave-uniform (SGPR)
    const float* irow = kINVD[ady];     // wave-uniform row pointer
    float sA[6];                         // kLG[adx]+kLG[ady]  (SGPR)
    float il2s[6][PX];
#pragma unroll
    for (int j = 0; j < 6; ++j) {
      sA[j] = kLG[j] + kg_ady;
      const float iv = irow[j];
#pragma unroll
      for (int p = 0; p < PX; ++p) il2s[j][p] = fminf(rc2[p] * iv, CLAMP2);
    }

#pragma unroll
    for (int u = 0; u < NU; ++u) {  // 12 tap columns serve PX pixels
      const float4 wv = wvs[u];
      const uint2 cv = cvs[u];
      const float tr = __uint_as_float(cv.x << 16);
      const float tg = __uint_as_float(cv.x & 0xffff0000u);
      const float tb = __uint_as_float(cv.y);
#pragma unroll
      for (int p = 0; p < PX; ++p) {
        const int dx = u - RAD - p;
        if (dx < -RAD || dx > RAD) continue;
        const int adx = dx < 0 ? -dx : dx;
        // f = clamp(dot,?) - 1, with the -1 folded into the dot chain
        const float d1 = fmaf(wv.x, cnx[p],
                         fmaf(wv.y, cny[p], fmaf(wv.z, cnz[p], -1.0f)));
        const float f = fmaxf(d1, -1.0f);
        // ct = sA - |z_t - z_c| * il2   (exponent sans normal term)
        const float dz = wv.w - czv[p];
        const float ct = fmaf(-fabsf(dz), il2s[adx][p], sA[adx]);
        // e = 128*log2(dot) + ct via cubic in f; f=-1 -> e<=-338 -> w==0
        const float t1 = fmaf(f, PC3, PC2);
        const float t2 = fmaf(f, t1, PC1);
        const float e = fmaf(f, t2, ct);
        const float w = __builtin_amdgcn_exp2f(e);
        accx[p] = fmaf(tr, w, accx[p]);
        accy[p] = fmaf(tg, w, accy[p]);
        accz[p] = fmaf(tb, w, accz[p]);
        accw[p] += w;
      }
    }
  }

#pragma unroll
  for (int p = 0; p < PX; ++p) {
    const int pix = plane + oy * W + ox0 + p;
    const float inv = 1.0f / accw[p];  // center tap weight==1 => accw>=1
    float* op = out + pix * 3;
    op[0] = accx[p] * inv;
    op[1] = accy[p] * inv;
    op[2] = accz[p] * inv;
  }
}

extern "C" void kernel_launch(void* const* d_in, const int* in_sizes, int n_in,
                              void* d_out, int out_size, void* d_ws, size_t ws_size,
                              hipStream_t stream) {
  const float* col = (const float*)d_in[0];
  const float* nrm = (const float*)d_in[1];
  const float* zdz = (const float*)d_in[2];
  float* out = (float*)d_out;
  const int H = 1024, W = 1024;
  const int B = in_sizes[0] / (3 * H * W);
  dim3 grid(W / BX, H / BY, B);
  bilateral_kernel<<<grid, dim3(NT), 0, stream>>>(col, nrm, zdz, out, H, W);
}